// Round 5
// baseline (64726.733 us; speedup 1.0000x reference)
//
#include <hip/hip_runtime.h>
#include <hip/hip_cooperative_groups.h>
#include <stdint.h>

#define NBLK 256          // launch size (prep uses all; recurrence uses NWORK)
#define NWORK 64          // working blocks: block m owns cols 16m for ALL 64 rows
#define NTHR 512          // 8 waves
#define BATCH 64
#define HD 1024
#define SEQ 512
#define FS 32             // flag line stride (ints) = 128B

typedef unsigned short u16;
typedef uint32_t u32;
typedef __attribute__((ext_vector_type(8))) short v8s;        // 8 bf16 (MFMA A/B frag)
typedef __attribute__((ext_vector_type(4))) float v4f;        // MFMA C/D frag
typedef __attribute__((ext_vector_type(4))) unsigned int v4u; // dwordx4

__device__ __forceinline__ float bf2f(u16 u){
  union { float f; u32 i; } c; c.i = ((u32)u) << 16; return c.f;
}
__device__ __forceinline__ u16 f2bf(float f){  // round-to-nearest-even
  union { float f; u32 i; } c; c.f = f;
  u32 i = c.i;
  return (u16)((i + 0x7fffu + ((i >> 16) & 1u)) >> 16);
}
__device__ __forceinline__ float sigm(float v){ return 1.f / (1.f + __expf(-v)); }

// packed activation element: low16 = hi bf16, high16 = lo bf16; value = hi + lo
__device__ __forceinline__ u32 packf(float v){
  const u16 hi = f2bf(v);
  const u16 lo = f2bf(v - bf2f(hi));
  return (u32)hi | ((u32)lo << 16);
}
__device__ __forceinline__ float unpackf(u32 w){
  return bf2f((u16)(w & 0xffffu)) + bf2f((u16)(w >> 16));
}

// agent-scope (MALL-coherent) scalar access
__device__ __forceinline__ int aldi(const int* p){
  return __hip_atomic_load(p, __ATOMIC_RELAXED, __HIP_MEMORY_SCOPE_AGENT);
}
__device__ __forceinline__ void ast_flag(int* p, int v){
  __hip_atomic_store(p, v, __ATOMIC_RELAXED, __HIP_MEMORY_SCOPE_AGENT);
}
// blocking agent dwordx4 load (pre-poll prefetch; wait included => rule-#18-safe)
__device__ __forceinline__ v4u ald4(const u32* p){
  v4u r;
  asm volatile("global_load_dwordx4 %0, %1, off sc0 sc1\n\ts_waitcnt vmcnt(0)"
               : "=v"(r) : "v"(p) : "memory");
  return r;
}
// agent dwordx4 / dword stores (drained by following __syncthreads before flag)
__device__ __forceinline__ void ast4(u32* p, v4u v){
  asm volatile("global_store_dwordx4 %0, %1, off sc0 sc1" :: "v"(p), "v"(v) : "memory");
}
__device__ __forceinline__ void ast1(u32* p, u32 v){
  asm volatile("global_store_dword %0, %1, off sc0 sc1" :: "v"(p), "v"(v) : "memory");
}

// ---- no-wait batched loads + counted-vmcnt pipeline (rule #18: SB0 after wait) ----
#define VMWAIT(N) do { asm volatile("s_waitcnt vmcnt(" #N ")" ::: "memory"); \
                       __builtin_amdgcn_sched_barrier(0); } while (0)

__device__ __forceinline__ void b8_nw(const u32* p, v4u r[8]){
  asm volatile(
    "global_load_dwordx4 %0, %8, off sc0 sc1\n\t"
    "global_load_dwordx4 %1, %8, off offset:16 sc0 sc1\n\t"
    "global_load_dwordx4 %2, %8, off offset:128 sc0 sc1\n\t"
    "global_load_dwordx4 %3, %8, off offset:144 sc0 sc1\n\t"
    "global_load_dwordx4 %4, %8, off offset:256 sc0 sc1\n\t"
    "global_load_dwordx4 %5, %8, off offset:272 sc0 sc1\n\t"
    "global_load_dwordx4 %6, %8, off offset:384 sc0 sc1\n\t"
    "global_load_dwordx4 %7, %8, off offset:400 sc0 sc1"
    : "=&v"(r[0]), "=&v"(r[1]), "=&v"(r[2]), "=&v"(r[3]),
      "=&v"(r[4]), "=&v"(r[5]), "=&v"(r[6]), "=&v"(r[7])
    : "v"(p) : "memory");
}
// internal-wait 16-load batch (gates A, 256 cols)
__device__ __forceinline__ void ald_batch16(const u32* p, v4u r[16]){
  asm volatile(
    "global_load_dwordx4 %0, %16, off sc0 sc1\n\t"
    "global_load_dwordx4 %1, %16, off offset:16 sc0 sc1\n\t"
    "global_load_dwordx4 %2, %16, off offset:128 sc0 sc1\n\t"
    "global_load_dwordx4 %3, %16, off offset:144 sc0 sc1\n\t"
    "global_load_dwordx4 %4, %16, off offset:256 sc0 sc1\n\t"
    "global_load_dwordx4 %5, %16, off offset:272 sc0 sc1\n\t"
    "global_load_dwordx4 %6, %16, off offset:384 sc0 sc1\n\t"
    "global_load_dwordx4 %7, %16, off offset:400 sc0 sc1\n\t"
    "global_load_dwordx4 %8, %16, off offset:512 sc0 sc1\n\t"
    "global_load_dwordx4 %9, %16, off offset:528 sc0 sc1\n\t"
    "global_load_dwordx4 %10, %16, off offset:640 sc0 sc1\n\t"
    "global_load_dwordx4 %11, %16, off offset:656 sc0 sc1\n\t"
    "global_load_dwordx4 %12, %16, off offset:768 sc0 sc1\n\t"
    "global_load_dwordx4 %13, %16, off offset:784 sc0 sc1\n\t"
    "global_load_dwordx4 %14, %16, off offset:896 sc0 sc1\n\t"
    "global_load_dwordx4 %15, %16, off offset:912 sc0 sc1\n\t"
    "s_waitcnt vmcnt(0)"
    : "=&v"(r[0]), "=&v"(r[1]), "=&v"(r[2]), "=&v"(r[3]),
      "=&v"(r[4]), "=&v"(r[5]), "=&v"(r[6]), "=&v"(r[7]),
      "=&v"(r[8]), "=&v"(r[9]), "=&v"(r[10]), "=&v"(r[11]),
      "=&v"(r[12]), "=&v"(r[13]), "=&v"(r[14]), "=&v"(r[15])
    : "v"(p) : "memory");
}

struct FragPair { v8s hi; v8s lo; };
__device__ __forceinline__ FragPair splitpair(v4u w0, v4u w1){
  union { v8s v; u32 u[4]; } H, L;
#pragma unroll
  for (int i = 0; i < 2; i++){
    H.u[i]     = (w0[2*i] & 0xffffu) | (w0[2*i+1] << 16);
    L.u[i]     = (w0[2*i] >> 16)     | (w0[2*i+1] & 0xffff0000u);
    H.u[2 + i] = (w1[2*i] & 0xffffu) | (w1[2*i+1] << 16);
    L.u[2 + i] = (w1[2*i] >> 16)     | (w1[2*i+1] & 0xffff0000u);
  }
  FragPair f; f.hi = H.v; f.lo = L.v; return f;
}

// ---- mog weight prefetch: ALL 4 k-steps hi/lo (plain cached loads) ----
struct MogPre { v8s bh[4]; v8s bl[4]; };
__device__ __forceinline__ MogPre mog_pre(const u16* WThi, const u16* WTlo, int cn, int tid){
  const int w = tid >> 6, lane = tid & 63;
  const int mi = lane & 15, q = lane >> 4;
  const int kb = w * 128 + q * 8;
  const u16* bh_p = WThi + (size_t)(cn + mi) * HD + kb;
  const u16* bl_p = WTlo + (size_t)(cn + mi) * HD + kb;
  MogPre pre;
#pragma unroll
  for (int ks = 0; ks < 4; ks++){
    pre.bh[ks] = *(const v8s*)(bh_p + ks * 32);
    pre.bl[ks] = *(const v8s*)(bl_p + ks * 32);
  }
  return pre;
}
// gates: ks=0 prefetched for all 4 gate n-tiles
struct GatesPre1 { v8s bh[4]; v8s bl[4]; };
__device__ __forceinline__ GatesPre1 gates_pre1(
    const u16* WihThi, const u16* WihTlo,
    const u16* WhhThi, const u16* WhhTlo, int cn, int tid){
  const int w = tid >> 6, lane = tid & 63;
  const int mi = lane & 15;
  const int q = lane >> 4;
  const int src = w >> 2;
  const u16* Bh = src ? WhhThi : WihThi;
  const u16* Bl = src ? WhhTlo : WihTlo;
  const int kb = (w & 3) * 256 + q * 8;
  GatesPre1 g;
#pragma unroll
  for (int nt = 0; nt < 4; nt++){
    const size_t brow = (size_t)(nt * HD + cn + mi) * HD + kb;
    g.bh[nt] = *(const v8s*)(Bh + brow);
    g.bl[nt] = *(const v8s*)(Bl + brow);
  }
  return g;
}

// one 16-row MFMA tile into cb (identical arithmetic + layout to verified R2 tile)
__device__ __forceinline__ void mog_tile(const MogPre& pre, v4u ar[8], float* cbt,
                                         int q, int mi){
  v4f acc = {0.f, 0.f, 0.f, 0.f};
#pragma unroll
  for (int ks = 0; ks < 4; ks++){
    FragPair a = splitpair(ar[2 * ks], ar[2 * ks + 1]);
    acc = __builtin_amdgcn_mfma_f32_16x16x32_bf16(a.hi, pre.bh[ks], acc, 0, 0, 0);
    acc = __builtin_amdgcn_mfma_f32_16x16x32_bf16(a.hi, pre.bl[ks], acc, 0, 0, 0);
    acc = __builtin_amdgcn_mfma_f32_16x16x32_bf16(a.lo, pre.bh[ks], acc, 0, 0, 0);
  }
#pragma unroll
  for (int r = 0; r < 4; r++) cbt[(q * 4 + r) * 17 + mi] = acc[r];
}

// ---- one mogrify phase, 64 rows x 16 cols: O = 2*sigmoid(A @ W) * mult ----
// A: all 64 rows, wave k-slice kb..kb+127 -> 8 producer blocks [8w, 8w+8).
// 32 A-loads issued no-wait, consumed via counted vmcnt (4 row-tiles pipelined).
__device__ __forceinline__ void mog_phase64(
    const MogPre& pre, const u32* A, int target,
    const float* xt, const u32* M, u32* O,
    int cn, int tid, const int* flags, float* cb)
{
  const int w = tid >> 6, lane = tid & 63;
  const int mi = lane & 15, q = lane >> 4;
  const int kb = w * 128 + q * 8;
  const int er = tid >> 2, ec4 = (tid & 3) * 4;   // epilogue: row er(0..63), 4 cols
  const bool epi = (tid < 256);
  float mx[4];
  if (epi){
    if (xt){
      const float4 xv = *(const float4*)(xt + (size_t)er * (SEQ * HD) + cn + ec4);
      mx[0] = xv.x; mx[1] = xv.y; mx[2] = xv.z; mx[3] = xv.w;
    } else {
      const v4u mv = ald4(M + (size_t)er * HD + cn + ec4);  // own-block prior output
#pragma unroll
      for (int j = 0; j < 4; j++) mx[j] = unpackf(mv[j]);
    }
  }
  // producer wait: 8 flags, one line each
  {
    const int* fp = flags + (8 * w + (lane & 7)) * FS;
    while (aldi(fp) < target) __builtin_amdgcn_s_sleep(1);
  }
  // A: 32 dwordx4 no-wait (4 row-tiles), then counted-vmcnt staged consumption
  v4u ar0[8], ar1[8], ar2[8], ar3[8];
  b8_nw(A + (size_t)(mi)      * HD + kb, ar0);
  b8_nw(A + (size_t)(16 + mi) * HD + kb, ar1);
  b8_nw(A + (size_t)(32 + mi) * HD + kb, ar2);
  b8_nw(A + (size_t)(48 + mi) * HD + kb, ar3);
  VMWAIT(24); mog_tile(pre, ar0, cb + (w * 4 + 0) * 272, q, mi);
  VMWAIT(16); mog_tile(pre, ar1, cb + (w * 4 + 1) * 272, q, mi);
  VMWAIT(8);  mog_tile(pre, ar2, cb + (w * 4 + 2) * 272, q, mi);
  VMWAIT(0);  mog_tile(pre, ar3, cb + (w * 4 + 3) * 272, q, mi);
  __syncthreads();
  if (epi){
    const int rt = er >> 4, rr = er & 15;
    v4u ov;
#pragma unroll
    for (int j = 0; j < 4; j++){
      float v = 0.f;
#pragma unroll
      for (int w2 = 0; w2 < 8; w2++)
        v += cb[(w2 * 4 + rt) * 272 + rr * 17 + (ec4 + j)];
      ov[j] = packf(2.f * sigm(v) * mx[j]);
    }
    ast4(O + (size_t)er * HD + cn + ec4, ov);
  }
  __syncthreads();   // drains all data stores before caller's flag store
}

// ---- gates + fused LSTM cell, 64 rows x 16 h-cols, 4 sequential row-tiles ----
__device__ __forceinline__ void gates_phase64(
    const GatesPre1& gp, const u32* X3, const u32* H2, int target,
    const u16* WihThi, const u16* WihTlo,
    const u16* WhhThi, const u16* WhhTlo,
    const float* bsum, float creg[4], u32* Oh, float* out, bool last,
    int cn, int tid, const int* flags, float* cb)
{
  const int w = tid >> 6, lane = tid & 63;
  const int mi = lane & 15, q = lane >> 4;
  const int src = w >> 2;                 // 0: X3@Wih (waves 0-3), 1: H2@Whh (4-7)
  const u32* Ap = src ? H2 : X3;
  const u16* Bh = src ? WhhThi : WihThi;
  const u16* Bl = src ? WhhTlo : WihTlo;
  const int kb = (w & 3) * 256 + q * 8;
  const u16* bh_p[4]; const u16* bl_p[4];
#pragma unroll
  for (int nt = 0; nt < 4; nt++){
    const size_t brow = (size_t)(nt * HD + cn + mi) * HD + kb;
    bh_p[nt] = Bh + brow; bl_p[nt] = Bl + brow;
  }
  // Wih waves wait on i5's 16 producers; Whh waves covered transitively by i5
  if (!src){
    const int* fp = flags + (16 * (w & 3) + (lane & 15)) * FS;
    while (aldi(fp) < target) __builtin_amdgcn_s_sleep(1);
  }
#pragma unroll
  for (int rt = 0; rt < 4; rt++){
    v4u ar[16];
    ald_batch16(Ap + (size_t)(16 * rt + mi) * HD + kb, ar);
    v4f acc[4];
#pragma unroll
    for (int nt = 0; nt < 4; nt++) acc[nt] = (v4f){0.f, 0.f, 0.f, 0.f};
#pragma unroll
    for (int ks = 0; ks < 8; ks++){
      FragPair a = splitpair(ar[2 * ks], ar[2 * ks + 1]);
#pragma unroll
      for (int nt = 0; nt < 4; nt++){
        v8s bh, bl;
        if (ks == 0){ bh = gp.bh[nt]; bl = gp.bl[nt]; }
        else { bh = *(const v8s*)(bh_p[nt] + ks * 32);
               bl = *(const v8s*)(bl_p[nt] + ks * 32); }
        acc[nt] = __builtin_amdgcn_mfma_f32_16x16x32_bf16(a.hi, bh, acc[nt], 0, 0, 0);
        acc[nt] = __builtin_amdgcn_mfma_f32_16x16x32_bf16(a.hi, bl, acc[nt], 0, 0, 0);
        acc[nt] = __builtin_amdgcn_mfma_f32_16x16x32_bf16(a.lo, bh, acc[nt], 0, 0, 0);
      }
    }
#pragma unroll
    for (int nt = 0; nt < 4; nt++)
#pragma unroll
      for (int r = 0; r < 4; r++)
        cb[(w * 4 + nt) * 272 + (q * 4 + r) * 17 + mi] = acc[nt][r];
    __syncthreads();
    if (tid < 256){
      const int r = tid >> 4, c = tid & 15;
      float g[4];
#pragma unroll
      for (int qq = 0; qq < 4; qq++){
        float v = 0.f;
#pragma unroll
        for (int w2 = 0; w2 < 8; w2++) v += cb[(w2 * 4 + qq) * 272 + r * 17 + c];
        g[qq] = v + bsum[qq];
      }
      const float ig = sigm(g[0]), fg = sigm(g[1]), cg = tanhf(g[2]), og = sigm(g[3]);
      const float cnew = fg * creg[rt] + ig * cg;
      creg[rt] = cnew;
      const float h = og * tanhf(cnew);
      const int gi = (16 * rt + r) * HD + (cn + c);
      ast1(Oh + gi, packf(h));
      if (last) out[gi] = h;
    }
    __syncthreads();   // drains stores; protects cb for next rt
  }
}

extern "C" __global__ void __launch_bounds__(NTHR, 2)
moglstm_kernel(const float* __restrict__ x, const float* __restrict__ Wih,
               const float* __restrict__ Whh, const float* __restrict__ bih,
               const float* __restrict__ bhh, const float* __restrict__ Q,
               const float* __restrict__ Rw, const float* __restrict__ h0,
               const float* __restrict__ c0, float* __restrict__ out,
               uint8_t* __restrict__ ws)
{
  __shared__ float cb[32 * 272];
  __shared__ u16 shh[32 * 33], shl[32 * 33];

  // ---- carve workspace ----
  const size_t ACT = (size_t)BATCH * HD;       // u32 per activation buffer (256KB)
  u32* P = (u32*)ws;
  u32* x1[2] = { P + 0 * ACT, P + 1 * ACT };
  u32* h1[2] = { P + 2 * ACT, P + 3 * ACT };
  u32* x2[2] = { P + 4 * ACT, P + 5 * ACT };
  u32* h2[2] = { P + 6 * ACT, P + 7 * ACT };
  u32* x3[2] = { P + 8 * ACT, P + 9 * ACT };
  u32* hb[2] = { P + 10 * ACT, P + 11 * ACT };
  uint8_t* p = (uint8_t*)(P + 12 * ACT);
  u16* QThi  = (u16*)p;  p += (size_t)HD * HD * 2;
  u16* QTlo  = (u16*)p;  p += (size_t)HD * HD * 2;
  u16* RThi  = (u16*)p;  p += (size_t)HD * HD * 2;
  u16* RTlo  = (u16*)p;  p += (size_t)HD * HD * 2;
  u16* WihThi = (u16*)p; p += (size_t)4 * HD * HD * 2;
  u16* WihTlo = (u16*)p; p += (size_t)4 * HD * HD * 2;
  u16* WhhThi = (u16*)p; p += (size_t)4 * HD * HD * 2;
  u16* WhhTlo = (u16*)p; p += (size_t)4 * HD * HD * 2;
  int* flags = (int*)p;                        // [NWORK * FS]

  const int bid = blockIdx.x, tid = threadIdx.x;

  // ---- prep (all 256 blocks): weights -> hi/lo bf16 transposed; init state ----
  for (int tile = bid; tile < 10240; tile += NBLK){
    const float* W; u16 *Th, *Tl; int N, kt, nt;
    if (tile < 1024)      { W = Q;   Th = QThi;   Tl = QTlo;   N = HD;     int tl = tile;        kt = tl >> 5; nt = tl & 31; }
    else if (tile < 2048) { W = Rw;  Th = RThi;   Tl = RTlo;   N = HD;     int tl = tile - 1024; kt = tl >> 5; nt = tl & 31; }
    else if (tile < 6144) { W = Wih; Th = WihThi; Tl = WihTlo; N = 4 * HD; int tl = tile - 2048; kt = tl >> 7; nt = tl & 127; }
    else                  { W = Whh; Th = WhhThi; Tl = WhhTlo; N = 4 * HD; int tl = tile - 6144; kt = tl >> 7; nt = tl & 127; }
    for (int e = tid; e < 1024; e += NTHR){
      const int ki = e >> 5, nj = e & 31;
      const float v = W[(size_t)(kt * 32 + ki) * N + nt * 32 + nj];
      const u16 hi = f2bf(v);
      shh[ki * 33 + nj] = hi;
      shl[ki * 33 + nj] = f2bf(v - bf2f(hi));
    }
    __syncthreads();
    for (int e = tid; e < 1024; e += NTHR){
      const int ni = e >> 5, kj = e & 31;
      Th[(size_t)(nt * 32 + ni) * HD + kt * 32 + kj] = shh[kj * 33 + ni];
      Tl[(size_t)(nt * 32 + ni) * HD + kt * 32 + kj] = shl[kj * 33 + ni];
    }
    __syncthreads();
  }
  // zero flags + h0 -> hb[1] (read by i1 at t=0, flag target 0 trivially satisfied)
  for (int i = bid * NTHR + tid; i < NWORK * FS; i += NBLK * NTHR)
    flags[i] = 0;
  for (int e = bid * NTHR + tid; e < BATCH * HD; e += NBLK * NTHR)
    hb[1][e] = packf(h0[e]);

  __threadfence();                          // flush prep's plain stores
  cooperative_groups::this_grid().sync();   // launch-robust full-grid barrier
  if (bid >= NWORK) return;

  const int cn = bid * 16;
  int* mf = flags + bid * FS;

  // per-thread (tid<256) cell state + bias sums: col cn+(tid&15), rows 16rt+(tid>>4)
  float creg[4] = {0.f, 0.f, 0.f, 0.f};
  float bsum[4] = {0.f, 0.f, 0.f, 0.f};
  if (tid < 256){
    const int r = tid >> 4, c = tid & 15, col = cn + c;
#pragma unroll
    for (int rt = 0; rt < 4; rt++) creg[rt] = c0[(16 * rt + r) * HD + col];
#pragma unroll
    for (int qq = 0; qq < 4; qq++) bsum[qq] = bih[qq * HD + col] + bhh[qq * HD + col];
  }

  // ---- recurrence: ONE 64-block group (no weight duplication), flag chain ----
  MogPre pre = mog_pre(QThi, QTlo, cn, tid);
  for (int t = 0; t < SEQ; t++){
    const int pb = t & 1;
    const u32* hrd = hb[pb ^ 1];   // h(t-1)
    u32*       hwr = hb[pb];       // h(t)
    u32 *x1p = x1[pb], *h1p = h1[pb], *x2p = x2[pb], *h2p = h2[pb], *x3p = x3[pb];
    const int b6 = 6 * t;

    // i1: xt1 = 2s(ht0@Q)*x[:,t,:]
    mog_phase64(pre, hrd, b6, x + (size_t)t * HD, nullptr, x1p, cn, tid, flags, cb);
    if (tid == 0) ast_flag(mf, b6 + 1);
    pre = mog_pre(RThi, RTlo, cn, tid);
    // i2: ht1 = 2s(xt1@R)*ht0
    mog_phase64(pre, x1p, b6 + 1, nullptr, hrd, h1p, cn, tid, flags, cb);
    if (tid == 0) ast_flag(mf, b6 + 2);
    pre = mog_pre(QThi, QTlo, cn, tid);
    // i3: xt2 = 2s(ht1@Q)*xt1
    mog_phase64(pre, h1p, b6 + 2, nullptr, x1p, x2p, cn, tid, flags, cb);
    if (tid == 0) ast_flag(mf, b6 + 3);
    pre = mog_pre(RThi, RTlo, cn, tid);
    // i4: ht2 = 2s(xt2@R)*ht1
    mog_phase64(pre, x2p, b6 + 3, nullptr, h1p, h2p, cn, tid, flags, cb);
    if (tid == 0) ast_flag(mf, b6 + 4);
    pre = mog_pre(QThi, QTlo, cn, tid);
    // i5: xt3 = 2s(ht2@Q)*xt2
    mog_phase64(pre, h2p, b6 + 4, nullptr, x2p, x3p, cn, tid, flags, cb);
    if (tid == 0) ast_flag(mf, b6 + 5);
    GatesPre1 gp = gates_pre1(WihThi, WihTlo, WhhThi, WhhTlo, cn, tid);
    // gates + cell -> h(t)
    gates_phase64(gp, x3p, h2p, b6 + 5, WihThi, WihTlo, WhhThi, WhhTlo,
                  bsum, creg, hwr, out, (t == SEQ - 1), cn, tid, flags, cb);
    if (tid == 0) ast_flag(mf, b6 + 6);
    pre = mog_pre(QThi, QTlo, cn, tid);
  }
}

extern "C" void kernel_launch(void* const* d_in, const int* in_sizes, int n_in,
                              void* d_out, int out_size, void* d_ws, size_t ws_size,
                              hipStream_t stream)
{
  const float* x   = (const float*)d_in[0];
  const float* Wih = (const float*)d_in[1];
  const float* Whh = (const float*)d_in[2];
  const float* bih = (const float*)d_in[3];
  const float* bhh = (const float*)d_in[4];
  const float* Q   = (const float*)d_in[5];
  const float* Rw  = (const float*)d_in[6];
  const float* h0  = (const float*)d_in[7];
  const float* c0  = (const float*)d_in[8];
  float* out = (float*)d_out;
  uint8_t* ws = (uint8_t*)d_ws;
  void* args[] = { &x, &Wih, &Whh, &bih, &bhh, &Q, &Rw, &h0, &c0, &out, &ws };
  hipLaunchCooperativeKernel((void*)moglstm_kernel, dim3(NBLK), dim3(NTHR),
                             args, 0, stream);
}